// Round 1
// baseline (231.166 us; speedup 1.0000x reference)
//
#include <hip/hip_runtime.h>
#include <hip/hip_bf16.h>
#include <stdint.h>

#define B_ 2
#define N_ 2048
#define DIM_ 1024
#define HEADS_ 16
#define DH_ 64
#define EPS_ 1e-5f

typedef __attribute__((ext_vector_type(4))) float f32x4;
typedef __attribute__((ext_vector_type(8))) __bf16 bf16x8;
typedef __attribute__((ext_vector_type(4))) unsigned int u32x4;

__device__ __forceinline__ f32x4 mfma16(bf16x8 a, bf16x8 b, f32x4 c) {
  return __builtin_amdgcn_mfma_f32_16x16x32_bf16(a, b, c, 0, 0, 0);
}

__device__ __forceinline__ unsigned short f2bf(float x) {
  unsigned int u = __builtin_bit_cast(unsigned int, x);
  u += 0x7fffu + ((u >> 16) & 1u);
  return (unsigned short)(u >> 16);
}

__device__ __forceinline__ bf16x8 ld_frag(const unsigned short* p) {
  u32x4 v = *reinterpret_cast<const u32x4*>(p);
  return __builtin_bit_cast(bf16x8, v);
}

__device__ __forceinline__ void gload_lds16(const unsigned short* g, unsigned short* l) {
  __builtin_amdgcn_global_load_lds((const __attribute__((address_space(1))) void*)g,
                                   (__attribute__((address_space(3))) void*)l, 16, 0, 0);
}

// Stage an NR x 64 bf16 tile (row stride ldg elems) into LDS with chunk-XOR
// swizzle: LDS slot (row, chunk c) holds global chunk c ^ (row & 7).
template <int NR>
__device__ __forceinline__ void stage_swz(const unsigned short* __restrict__ g, int ldg,
                                          unsigned short* lds, int tid) {
#pragma unroll
  for (int p = 0; p < NR * 8 / 256; ++p) {
    int flat = p * 256 + tid;  // 16B chunk id
    int row = flat >> 3, c = flat & 7;
    u32x4 v = *reinterpret_cast<const u32x4*>(g + (size_t)row * ldg + c * 8);
    int cs = c ^ (row & 7);
    *reinterpret_cast<u32x4*>(lds + row * 64 + cs * 8) = v;
  }
}

// ---------------- LayerNorm over sequence axis ----------------
__global__ __launch_bounds__(256) void ln_part(const float* __restrict__ x,
                                               float* __restrict__ ps,
                                               float* __restrict__ pss) {
  const int d = blockIdx.x * 256 + threadIdx.x;
  const int b = blockIdx.y >> 4, sp = blockIdx.y & 15;
  const float* xp = x + (size_t)(b * N_ + sp * 128) * DIM_ + d;
  float s = 0.f, ss = 0.f;
  for (int i = 0; i < 128; ++i) {
    float v = xp[(size_t)i * DIM_];
    s += v;
    ss += v * v;
  }
  int c = b * DIM_ + d;
  ps[sp * (B_ * DIM_) + c] = s;
  pss[sp * (B_ * DIM_) + c] = ss;
}

__global__ void ln_fin(const float* __restrict__ ps, const float* __restrict__ pss,
                       const float* __restrict__ g, float* __restrict__ meanA,
                       float* __restrict__ sclA) {
  int c = blockIdx.x * 256 + threadIdx.x;
  float s = 0.f, ss = 0.f;
#pragma unroll
  for (int sp = 0; sp < 16; ++sp) {
    s += ps[sp * (B_ * DIM_) + c];
    ss += pss[sp * (B_ * DIM_) + c];
  }
  float m = s * (1.f / N_);
  float v = ss * (1.f / N_) - m * m;
  meanA[c] = m;
  sclA[c] = rsqrtf(fmaxf(v, EPS_)) * g[c & (DIM_ - 1)];
}

__global__ __launch_bounds__(256) void ln_apply(const float* __restrict__ x,
                                                const float* __restrict__ meanA,
                                                const float* __restrict__ sclA,
                                                unsigned short* __restrict__ xn) {
  size_t t = (size_t)blockIdx.x * 256 + threadIdx.x;
  size_t base = t * 8;
  int d0 = (int)(base & (DIM_ - 1));
  int b = base >= (size_t)N_ * DIM_;
  int c = b * DIM_ + d0;
  const float4* xp = reinterpret_cast<const float4*>(x + base);
  const float4* mp = reinterpret_cast<const float4*>(meanA + c);
  const float4* sp = reinterpret_cast<const float4*>(sclA + c);
  float4 x0 = xp[0], x1 = xp[1];
  float4 m0 = mp[0], m1 = mp[1];
  float4 s0 = sp[0], s1 = sp[1];
  union {
    unsigned short u[8];
    u32x4 v;
  } o;
  o.u[0] = f2bf((x0.x - m0.x) * s0.x);
  o.u[1] = f2bf((x0.y - m0.y) * s0.y);
  o.u[2] = f2bf((x0.z - m0.z) * s0.z);
  o.u[3] = f2bf((x0.w - m0.w) * s0.w);
  o.u[4] = f2bf((x1.x - m1.x) * s1.x);
  o.u[5] = f2bf((x1.y - m1.y) * s1.y);
  o.u[6] = f2bf((x1.z - m1.z) * s1.z);
  o.u[7] = f2bf((x1.w - m1.w) * s1.w);
  *reinterpret_cast<u32x4*>(xn + base) = o.v;
}

// ---------------- fp32 -> bf16 weight cast (optional scale) ----------------
__global__ __launch_bounds__(256) void cast_bf16(const float* __restrict__ src,
                                                 unsigned short* __restrict__ dst, float scale) {
  size_t t = (size_t)blockIdx.x * 256 + threadIdx.x;
  size_t base = t * 8;
  const float4* sp = reinterpret_cast<const float4*>(src + base);
  float4 a = sp[0], b4 = sp[1];
  union {
    unsigned short u[8];
    u32x4 v;
  } o;
  o.u[0] = f2bf(a.x * scale);
  o.u[1] = f2bf(a.y * scale);
  o.u[2] = f2bf(a.z * scale);
  o.u[3] = f2bf(a.w * scale);
  o.u[4] = f2bf(b4.x * scale);
  o.u[5] = f2bf(b4.y * scale);
  o.u[6] = f2bf(b4.z * scale);
  o.u[7] = f2bf(b4.w * scale);
  *reinterpret_cast<u32x4*>(dst + base) = o.v;
}

// ---------------- GEMM: C[M,Nc] = A[M,K]bf16 * W[Nc,K]bf16^T ----------------
// 128x128 tile, BK=64, 4 waves (2x2), 4x4 16x16x32 frags per wave.
template <bool OUT_F32>
__global__ __launch_bounds__(256) void gemm_bt(const unsigned short* __restrict__ A,
                                               const unsigned short* __restrict__ W,
                                               void* __restrict__ Cout, int K, int ldc) {
  __shared__ unsigned short sA[128 * 64];
  __shared__ unsigned short sB[128 * 64];
  const int tid = threadIdx.x, lane = tid & 63, w = tid >> 6;
  const int wm = w >> 1, wn = w & 1;
  const int l15 = lane & 15, l4 = lane >> 4;
  const int m0 = blockIdx.y * 128, n0 = blockIdx.x * 128;
  f32x4 acc[4][4] = {};
  for (int kt = 0; kt < K; kt += 64) {
    __syncthreads();
#pragma unroll
    for (int p = 0; p < 4; ++p) {
      int flat = p * 256 + tid;
      int row = flat >> 3, c = flat & 7;
      int cs = c ^ (row & 7);  // pre-swizzled global source, linear LDS dest
      gload_lds16(A + (size_t)(m0 + row) * K + kt + cs * 8, sA + (size_t)(p * 256 + w * 64) * 8);
      gload_lds16(W + (size_t)(n0 + row) * K + kt + cs * 8, sB + (size_t)(p * 256 + w * 64) * 8);
    }
    __syncthreads();
#pragma unroll
    for (int kk = 0; kk < 2; ++kk) {
      bf16x8 af[4], bfr[4];
#pragma unroll
      for (int i = 0; i < 4; ++i) {
        int rowA = wm * 64 + i * 16 + l15;
        af[i] = ld_frag(sA + rowA * 64 + (((kk * 4 + l4) ^ (rowA & 7)) * 8));
        int rowB = wn * 64 + i * 16 + l15;
        bfr[i] = ld_frag(sB + rowB * 64 + (((kk * 4 + l4) ^ (rowB & 7)) * 8));
      }
#pragma unroll
      for (int i = 0; i < 4; ++i)
#pragma unroll
        for (int j = 0; j < 4; ++j) acc[i][j] = mfma16(af[i], bfr[j], acc[i][j]);
    }
  }
#pragma unroll
  for (int i = 0; i < 4; ++i)
#pragma unroll
    for (int j = 0; j < 4; ++j)
#pragma unroll
      for (int r = 0; r < 4; ++r) {
        size_t off =
            (size_t)(m0 + wm * 64 + i * 16 + l4 * 4 + r) * ldc + (n0 + wn * 64 + j * 16 + l15);
        if (OUT_F32)
          ((float*)Cout)[off] = acc[i][j][r];
        else
          ((unsigned short*)Cout)[off] = f2bf(acc[i][j][r]);
      }
}

// ---------------- V transpose: qkv v-block -> Vt[b][h][dh][n] ----------------
__global__ __launch_bounds__(256) void transpose_v(const unsigned short* __restrict__ qkv,
                                                   unsigned short* __restrict__ Vt) {
  __shared__ unsigned short tt[64][65];
  const int tid = threadIdx.x;
  const int h = blockIdx.y >> 1, b = blockIdx.y & 1;
  const int n0 = blockIdx.x * 64;
  const unsigned short* src = qkv + (size_t)(b * N_ + n0) * 3072 + 2048 + h * 64;
#pragma unroll
  for (int i = 0; i < 16; ++i) {
    int idx = i * 256 + tid;
    int r = idx >> 6, c = idx & 63;
    tt[r][c] = src[(size_t)r * 3072 + c];
  }
  __syncthreads();
  unsigned short* dst = Vt + (size_t)(b * HEADS_ + h) * 64 * N_ + n0;
#pragma unroll
  for (int i = 0; i < 16; ++i) {
    int idx = i * 256 + tid;
    int dh = idx >> 6, nn = idx & 63;
    dst[(size_t)dh * N_ + nn] = tt[nn][dh];
  }
}

// ---------------- Flash attention with rel_pos_bias ----------------
// Block: 128 q-rows of one (b,h); 4 waves x 32 rows. K/V tiles of 64.
__global__ __launch_bounds__(256) void flash_attn(const unsigned short* __restrict__ qkv,
                                                  const float* __restrict__ bias,
                                                  const unsigned short* __restrict__ Vt,
                                                  unsigned short* __restrict__ Oatt) {
  __shared__ unsigned short sQ[128 * 64];  // Q; reused as P after q-frag hoist
  __shared__ unsigned short sK[64 * 64];
  __shared__ unsigned short sV[64 * 64];
  const int tid = threadIdx.x, lane = tid & 63, w = tid >> 6;
  const int l15 = lane & 15, l4 = lane >> 4;
  const int h = blockIdx.y >> 1, b = blockIdx.y & 1;
  const int i0 = blockIdx.x * 128;
  const unsigned short* Qg = qkv + (size_t)(b * N_ + i0) * 3072 + h * 64;
  const unsigned short* Kg = qkv + (size_t)b * N_ * 3072 + 1024 + h * 64;
  const unsigned short* VtB = Vt + (size_t)(b * HEADS_ + h) * 64 * N_;
  const float* bias_h = bias + (size_t)h * N_ * N_;

  stage_swz<128>(Qg, 3072, sQ, tid);
  stage_swz<64>(Kg, 3072, sK, tid);
  stage_swz<64>(VtB, N_, sV, tid);
  __syncthreads();

  bf16x8 qf[2][2];
#pragma unroll
  for (int mi = 0; mi < 2; ++mi)
#pragma unroll
    for (int kk = 0; kk < 2; ++kk) {
      int row = w * 32 + mi * 16 + l15;
      int c = (kk * 4 + l4) ^ (row & 7);
      qf[mi][kk] = ld_frag(sQ + row * 64 + c * 8);
    }

  f32x4 o[2][4] = {};
  float m_r[2][4], l_r[2][4];
#pragma unroll
  for (int mi = 0; mi < 2; ++mi)
#pragma unroll
    for (int r = 0; r < 4; ++r) {
      m_r[mi][r] = -1e30f;
      l_r[mi][r] = 0.f;
    }

  for (int jt = 0; jt < N_; jt += 64) {
    if (jt) {
      __syncthreads();
      stage_swz<64>(Kg + (size_t)jt * 3072, 3072, sK, tid);
      stage_swz<64>(VtB + jt, N_, sV, tid);
      __syncthreads();
    }
    // S = Q K^T (q pre-scaled via wq)
    bf16x8 kf[4][2];
#pragma unroll
    for (int nj = 0; nj < 4; ++nj)
#pragma unroll
      for (int kk = 0; kk < 2; ++kk) {
        int row = nj * 16 + l15;
        int c = (kk * 4 + l4) ^ (row & 7);
        kf[nj][kk] = ld_frag(sK + row * 64 + c * 8);
      }
    f32x4 s[2][4] = {};
#pragma unroll
    for (int mi = 0; mi < 2; ++mi)
#pragma unroll
      for (int nj = 0; nj < 4; ++nj)
#pragma unroll
        for (int kk = 0; kk < 2; ++kk) s[mi][nj] = mfma16(qf[mi][kk], kf[nj][kk], s[mi][nj]);

#pragma unroll
    for (int mi = 0; mi < 2; ++mi) {
      int ib = i0 + w * 32 + mi * 16 + l4 * 4;
      float sv[4][4];
#pragma unroll
      for (int nj = 0; nj < 4; ++nj) {
        const float* bp = bias_h + (size_t)ib * N_ + jt + nj * 16 + l15;
#pragma unroll
        for (int r = 0; r < 4; ++r) sv[nj][r] = s[mi][nj][r] + bp[r * N_];
      }
#pragma unroll
      for (int r = 0; r < 4; ++r) {
        float tm = fmaxf(fmaxf(sv[0][r], sv[1][r]), fmaxf(sv[2][r], sv[3][r]));
#pragma unroll
        for (int msk = 1; msk < 16; msk <<= 1) tm = fmaxf(tm, __shfl_xor(tm, msk));
        float mn = fmaxf(m_r[mi][r], tm);
        float alpha = __expf(m_r[mi][r] - mn);
        float rs = 0.f;
#pragma unroll
        for (int nj = 0; nj < 4; ++nj) {
          float p = __expf(sv[nj][r] - mn);
          sv[nj][r] = p;
          rs += p;
        }
#pragma unroll
        for (int msk = 1; msk < 16; msk <<= 1) rs += __shfl_xor(rs, msk);
        l_r[mi][r] = l_r[mi][r] * alpha + rs;
        m_r[mi][r] = mn;
#pragma unroll
        for (int fc = 0; fc < 4; ++fc) o[mi][fc][r] *= alpha;
      }
      // P -> LDS (wave-local rows; same swizzle as reads)
#pragma unroll
      for (int r = 0; r < 4; ++r)
#pragma unroll
        for (int nj = 0; nj < 4; ++nj) {
          int row = w * 32 + mi * 16 + l4 * 4 + r;
          int col = nj * 16 + l15;
          int cc = (col >> 3) ^ (row & 7);
          sQ[row * 64 + cc * 8 + (col & 7)] = f2bf(sv[nj][r]);
        }
    }
    // O += P V
    bf16x8 pf[2][2], vf[4][2];
#pragma unroll
    for (int mi = 0; mi < 2; ++mi)
#pragma unroll
      for (int kk = 0; kk < 2; ++kk) {
        int row = w * 32 + mi * 16 + l15;
        int c = (kk * 4 + l4) ^ (row & 7);
        pf[mi][kk] = ld_frag(sQ + row * 64 + c * 8);
      }
#pragma unroll
    for (int fc = 0; fc < 4; ++fc)
#pragma unroll
      for (int kk = 0; kk < 2; ++kk) {
        int row = fc * 16 + l15;
        int c = (kk * 4 + l4) ^ (row & 7);
        vf[fc][kk] = ld_frag(sV + row * 64 + c * 8);
      }
#pragma unroll
    for (int mi = 0; mi < 2; ++mi)
#pragma unroll
      for (int fc = 0; fc < 4; ++fc)
#pragma unroll
        for (int kk = 0; kk < 2; ++kk) o[mi][fc] = mfma16(pf[mi][kk], vf[fc][kk], o[mi][fc]);
  }
#pragma unroll
  for (int mi = 0; mi < 2; ++mi)
#pragma unroll
    for (int fc = 0; fc < 4; ++fc)
#pragma unroll
      for (int r = 0; r < 4; ++r) {
        int row = b * N_ + i0 + w * 32 + mi * 16 + l4 * 4 + r;
        int col = h * 64 + fc * 16 + l15;
        Oatt[(size_t)row * 1024 + col] = f2bf(o[mi][fc][r] / l_r[mi][r]);
      }
}

extern "C" void kernel_launch(void* const* d_in, const int* in_sizes, int n_in, void* d_out,
                              int out_size, void* d_ws, size_t ws_size, hipStream_t stream) {
  const float* x = (const float*)d_in[0];
  const float* bias = (const float*)d_in[1];
  const float* g = (const float*)d_in[2];
  const float* wq = (const float*)d_in[3];
  const float* wkv = (const float*)d_in[4];
  const float* wout = (const float*)d_in[5];
  float* out = (float*)d_out;

  float* ps = (float*)d_ws;                 // 16 * 2048
  float* pss = ps + 16 * B_ * DIM_;         // 16 * 2048
  float* meanA = pss + 16 * B_ * DIM_;      // 2048
  float* sclA = meanA + B_ * DIM_;          // 2048
  unsigned short* xn = (unsigned short*)(sclA + B_ * DIM_);  // 4096*1024 bf16
  unsigned short* Wqkv = xn + (size_t)4096 * 1024;           // 3072*1024 bf16
  unsigned short* WoutB = Wqkv + (size_t)3072 * 1024;        // 1024*1024 bf16
  unsigned short* qkvb = WoutB + (size_t)1024 * 1024;        // 4096*3072 bf16
  unsigned short* Vt = qkvb + (size_t)4096 * 3072;           // 2*16*64*2048 bf16
  unsigned short* Oatt = xn;  // alias: xn dead after QKV GEMM

  ln_part<<<dim3(DIM_ / 256, B_ * 16), 256, 0, stream>>>(x, ps, pss);
  ln_fin<<<dim3((B_ * DIM_) / 256), 256, 0, stream>>>(ps, pss, g, meanA, sclA);
  ln_apply<<<dim3((B_ * N_ * DIM_) / 2048), 256, 0, stream>>>(x, meanA, sclA, xn);
  cast_bf16<<<dim3((DIM_ * DIM_) / 2048), 256, 0, stream>>>(wq, Wqkv, 0.125f);  // q pre-scale
  cast_bf16<<<dim3((2 * DIM_ * DIM_) / 2048), 256, 0, stream>>>(wkv, Wqkv + (size_t)DIM_ * DIM_,
                                                                1.0f);
  cast_bf16<<<dim3((DIM_ * DIM_) / 2048), 256, 0, stream>>>(wout, WoutB, 1.0f);
  gemm_bt<false><<<dim3(3072 / 128, 4096 / 128), 256, 0, stream>>>(xn, Wqkv, qkvb, DIM_, 3072);
  transpose_v<<<dim3(N_ / 64, B_ * HEADS_), 256, 0, stream>>>(qkvb, Vt);
  flash_attn<<<dim3(N_ / 128, B_ * HEADS_), 256, 0, stream>>>(qkvb, bias, Vt, Oatt);
  gemm_bt<true><<<dim3(1024 / 128, 4096 / 128), 256, 0, stream>>>(Oatt, WoutB, out, DIM_, 1024);
}

// Round 2
// 216.890 us; speedup vs baseline: 1.0658x; 1.0658x over previous
//
#include <hip/hip_runtime.h>
#include <hip/hip_bf16.h>
#include <stdint.h>

#define B_ 2
#define N_ 2048
#define DIM_ 1024
#define HEADS_ 16
#define DH_ 64
#define EPS_ 1e-5f

typedef __attribute__((ext_vector_type(4))) float f32x4;
typedef __attribute__((ext_vector_type(8))) __bf16 bf16x8;
typedef __attribute__((ext_vector_type(4))) unsigned int u32x4;

__device__ __forceinline__ f32x4 mfma16(bf16x8 a, bf16x8 b, f32x4 c) {
  return __builtin_amdgcn_mfma_f32_16x16x32_bf16(a, b, c, 0, 0, 0);
}

__device__ __forceinline__ unsigned short f2bf(float x) {
  unsigned int u = __builtin_bit_cast(unsigned int, x);
  u += 0x7fffu + ((u >> 16) & 1u);
  return (unsigned short)(u >> 16);
}

__device__ __forceinline__ unsigned int cvt_pk_bf16(float lo, float hi) {
  unsigned int r;
  asm("v_cvt_pk_bf16_f32 %0, %1, %2" : "=v"(r) : "v"(lo), "v"(hi));
  return r;
}

__device__ __forceinline__ bf16x8 ld_frag(const unsigned short* p) {
  u32x4 v = *reinterpret_cast<const u32x4*>(p);
  return __builtin_bit_cast(bf16x8, v);
}

__device__ __forceinline__ void gload_lds16(const unsigned short* g, unsigned short* l) {
  __builtin_amdgcn_global_load_lds((const __attribute__((address_space(1))) void*)g,
                                   (__attribute__((address_space(3))) void*)l, 16, 0, 0);
}

// ---------------- LayerNorm over sequence axis ----------------
__global__ __launch_bounds__(256) void ln_part(const float* __restrict__ x,
                                               float* __restrict__ ps,
                                               float* __restrict__ pss) {
  const int d = blockIdx.x * 256 + threadIdx.x;
  const int b = blockIdx.y >> 4, sp = blockIdx.y & 15;
  const float* xp = x + (size_t)(b * N_ + sp * 128) * DIM_ + d;
  float s = 0.f, ss = 0.f;
  for (int i = 0; i < 128; ++i) {
    float v = xp[(size_t)i * DIM_];
    s += v;
    ss += v * v;
  }
  int c = b * DIM_ + d;
  ps[sp * (B_ * DIM_) + c] = s;
  pss[sp * (B_ * DIM_) + c] = ss;
}

__global__ void ln_fin(const float* __restrict__ ps, const float* __restrict__ pss,
                       const float* __restrict__ g, float* __restrict__ meanA,
                       float* __restrict__ sclA) {
  int c = blockIdx.x * 256 + threadIdx.x;
  float s = 0.f, ss = 0.f;
#pragma unroll
  for (int sp = 0; sp < 16; ++sp) {
    s += ps[sp * (B_ * DIM_) + c];
    ss += pss[sp * (B_ * DIM_) + c];
  }
  float m = s * (1.f / N_);
  float v = ss * (1.f / N_) - m * m;
  meanA[c] = m;
  sclA[c] = rsqrtf(fmaxf(v, EPS_)) * g[c & (DIM_ - 1)];
}

__global__ __launch_bounds__(256) void ln_apply(const float* __restrict__ x,
                                                const float* __restrict__ meanA,
                                                const float* __restrict__ sclA,
                                                unsigned short* __restrict__ xn) {
  size_t t = (size_t)blockIdx.x * 256 + threadIdx.x;
  size_t base = t * 8;
  int d0 = (int)(base & (DIM_ - 1));
  int b = base >= (size_t)N_ * DIM_;
  int c = b * DIM_ + d0;
  const float4* xp = reinterpret_cast<const float4*>(x + base);
  const float4* mp = reinterpret_cast<const float4*>(meanA + c);
  const float4* sp = reinterpret_cast<const float4*>(sclA + c);
  float4 x0 = xp[0], x1 = xp[1];
  float4 m0 = mp[0], m1 = mp[1];
  float4 s0 = sp[0], s1 = sp[1];
  union {
    unsigned short u[8];
    u32x4 v;
  } o;
  o.u[0] = f2bf((x0.x - m0.x) * s0.x);
  o.u[1] = f2bf((x0.y - m0.y) * s0.y);
  o.u[2] = f2bf((x0.z - m0.z) * s0.z);
  o.u[3] = f2bf((x0.w - m0.w) * s0.w);
  o.u[4] = f2bf((x1.x - m1.x) * s1.x);
  o.u[5] = f2bf((x1.y - m1.y) * s1.y);
  o.u[6] = f2bf((x1.z - m1.z) * s1.z);
  o.u[7] = f2bf((x1.w - m1.w) * s1.w);
  *reinterpret_cast<u32x4*>(xn + base) = o.v;
}

// ---------------- fp32 -> bf16 weight cast (optional scale) ----------------
__global__ __launch_bounds__(256) void cast_bf16(const float* __restrict__ src,
                                                 unsigned short* __restrict__ dst, float scale) {
  size_t t = (size_t)blockIdx.x * 256 + threadIdx.x;
  size_t base = t * 8;
  const float4* sp = reinterpret_cast<const float4*>(src + base);
  float4 a = sp[0], b4 = sp[1];
  union {
    unsigned short u[8];
    u32x4 v;
  } o;
  o.u[0] = f2bf(a.x * scale);
  o.u[1] = f2bf(a.y * scale);
  o.u[2] = f2bf(a.z * scale);
  o.u[3] = f2bf(a.w * scale);
  o.u[4] = f2bf(b4.x * scale);
  o.u[5] = f2bf(b4.y * scale);
  o.u[6] = f2bf(b4.z * scale);
  o.u[7] = f2bf(b4.w * scale);
  *reinterpret_cast<u32x4*>(dst + base) = o.v;
}

// ---------------- GEMM: C[M,Nc] = A[M,K]bf16 * W[Nc,K]bf16^T ----------------
template <bool OUT_F32>
__global__ __launch_bounds__(256) void gemm_bt(const unsigned short* __restrict__ A,
                                               const unsigned short* __restrict__ W,
                                               void* __restrict__ Cout, int K, int ldc) {
  __shared__ unsigned short sA[128 * 64];
  __shared__ unsigned short sB[128 * 64];
  const int tid = threadIdx.x, lane = tid & 63, w = tid >> 6;
  const int wm = w >> 1, wn = w & 1;
  const int l15 = lane & 15, l4 = lane >> 4;
  const int m0 = blockIdx.y * 128, n0 = blockIdx.x * 128;
  f32x4 acc[4][4] = {};
  for (int kt = 0; kt < K; kt += 64) {
    __syncthreads();
#pragma unroll
    for (int p = 0; p < 4; ++p) {
      int flat = p * 256 + tid;
      int row = flat >> 3, c = flat & 7;
      int cs = c ^ (row & 7);
      gload_lds16(A + (size_t)(m0 + row) * K + kt + cs * 8, sA + (size_t)(p * 256 + w * 64) * 8);
      gload_lds16(W + (size_t)(n0 + row) * K + kt + cs * 8, sB + (size_t)(p * 256 + w * 64) * 8);
    }
    __syncthreads();
#pragma unroll
    for (int kk = 0; kk < 2; ++kk) {
      bf16x8 af[4], bfr[4];
#pragma unroll
      for (int i = 0; i < 4; ++i) {
        int rowA = wm * 64 + i * 16 + l15;
        af[i] = ld_frag(sA + rowA * 64 + (((kk * 4 + l4) ^ (rowA & 7)) * 8));
        int rowB = wn * 64 + i * 16 + l15;
        bfr[i] = ld_frag(sB + rowB * 64 + (((kk * 4 + l4) ^ (rowB & 7)) * 8));
      }
#pragma unroll
      for (int i = 0; i < 4; ++i)
#pragma unroll
        for (int j = 0; j < 4; ++j) acc[i][j] = mfma16(af[i], bfr[j], acc[i][j]);
    }
  }
#pragma unroll
  for (int i = 0; i < 4; ++i)
#pragma unroll
    for (int j = 0; j < 4; ++j)
#pragma unroll
      for (int r = 0; r < 4; ++r) {
        size_t off =
            (size_t)(m0 + wm * 64 + i * 16 + l4 * 4 + r) * ldc + (n0 + wn * 64 + j * 16 + l15);
        if (OUT_F32)
          ((float*)Cout)[off] = acc[i][j][r];
        else
          ((unsigned short*)Cout)[off] = f2bf(acc[i][j][r]);
      }
}

// ---------------- V transpose: qkv v-block -> Vt[b][h][dh][n] ----------------
__global__ __launch_bounds__(256) void transpose_v(const unsigned short* __restrict__ qkv,
                                                   unsigned short* __restrict__ Vt) {
  __shared__ unsigned short tt[64][65];
  const int tid = threadIdx.x;
  const int h = blockIdx.y >> 1, b = blockIdx.y & 1;
  const int n0 = blockIdx.x * 64;
  const unsigned short* src = qkv + (size_t)(b * N_ + n0) * 3072 + 2048 + h * 64;
#pragma unroll
  for (int i = 0; i < 16; ++i) {
    int idx = i * 256 + tid;
    int r = idx >> 6, c = idx & 63;
    tt[r][c] = src[(size_t)r * 3072 + c];
  }
  __syncthreads();
  unsigned short* dst = Vt + (size_t)(b * HEADS_ + h) * 64 * N_ + n0;
#pragma unroll
  for (int i = 0; i < 16; ++i) {
    int idx = i * 256 + tid;
    int dh = idx >> 6, nn = idx & 63;
    dst[(size_t)dh * N_ + nn] = tt[nn][dh];
  }
}

// ---------------- Flash attention (swapped layout, 8 waves, dbuf K/V) -------
// Block: 128 q-rows of one (b,h); wave w owns q-rows w*16..w*16+15 (q = l15).
// S^T = K Q^T  (C: col=q=l15, row=key=l4*4+r)
// O^T = V^T P^T (C: col=q=l15, row=d=l4*4+r)
__global__ __launch_bounds__(512, 4) void flash_attn(const unsigned short* __restrict__ qkv,
                                                     const float* __restrict__ bias,
                                                     const unsigned short* __restrict__ Vt,
                                                     unsigned short* __restrict__ Oatt) {
  __shared__ unsigned short sK[2][64 * 64];  // swizzled K tiles (double buffer)
  __shared__ unsigned short sV[2][64 * 64];  // swizzled V^T tiles (double buffer)
  __shared__ unsigned short sP[8 * 16 * 64];  // per-wave P^T->P packed region

  const int tid = threadIdx.x, lane = tid & 63, w = tid >> 6;
  const int l15 = lane & 15, l4 = lane >> 4;
  const int h = blockIdx.y >> 1, b = blockIdx.y & 1;
  const int i0 = blockIdx.x * 128;

  const unsigned short* Kg = qkv + (size_t)b * N_ * 3072 + 1024 + h * 64;
  const unsigned short* VtB = Vt + (size_t)(b * HEADS_ + h) * 64 * N_;
  const float* bias_q = bias + (size_t)(i0 + w * 16 + l15) * N_ + (size_t)h * N_ * N_;

  // staging indices (one 16B chunk of K and one of V per thread per tile)
  const int srow = tid >> 3, sc = tid & 7;
  const int scs = sc ^ (srow & 7);
  const size_t kSrcOff = (size_t)srow * 3072 + (size_t)scs * 8;
  const size_t vSrcOff = (size_t)srow * N_ + (size_t)scs * 8;
  unsigned short* kDst0 = sK[0] + (size_t)w * 512;
  unsigned short* kDst1 = sK[1] + (size_t)w * 512;
  unsigned short* vDst0 = sV[0] + (size_t)w * 512;
  unsigned short* vDst1 = sV[1] + (size_t)w * 512;

  // Q straight to registers (B-operand frag: row q=l15, d-chunk l4)
  bf16x8 qf[2];
  {
    const unsigned short* Qg =
        qkv + (size_t)(b * N_ + i0 + w * 16 + l15) * 3072 + h * 64 + l4 * 8;
    qf[0] = ld_frag(Qg);
    qf[1] = ld_frag(Qg + 32);
  }

  // prologue: stage tile 0
  gload_lds16(Kg + kSrcOff, kDst0);
  gload_lds16(VtB + vSrcOff, vDst0);
  __syncthreads();

  f32x4 o_t[4] = {};
  float m_run = -1e30f, l_run = 0.f;

  unsigned int* sPu = reinterpret_cast<unsigned int*>(sP + (size_t)w * 16 * 64);
  const unsigned short* sPw = sP + (size_t)w * 16 * 64;

  const int NT = N_ / 64;
  for (int t = 0; t < NT; ++t) {
    const int cur = t & 1;
    // prefetch next tile (stays in flight across this tile's compute)
    if (t + 1 < NT) {
      const size_t jn = (size_t)(t + 1) * 64;
      gload_lds16(Kg + jn * 3072 + kSrcOff, cur ? kDst0 : kDst1);
      gload_lds16(VtB + jn + vSrcOff, cur ? vDst0 : vDst1);
    }
    const unsigned short* sKc = sK[cur];
    const unsigned short* sVc = sV[cur];

    // S^T = K Q^T
    f32x4 st[4];
    __builtin_amdgcn_s_setprio(1);
#pragma unroll
    for (int kj = 0; kj < 4; ++kj) {
      int row = kj * 16 + l15;
      bf16x8 kf0 = ld_frag(sKc + row * 64 + ((l4 ^ (l15 & 7)) * 8));
      bf16x8 kf1 = ld_frag(sKc + row * 64 + (((4 + l4) ^ (l15 & 7)) * 8));
      f32x4 z = {};
      z = mfma16(kf0, qf[0], z);
      st[kj] = mfma16(kf1, qf[1], z);
    }
    __builtin_amdgcn_s_setprio(0);

    // bias add (float4 per kj: keys jt + kj*16 + l4*4 .. +3 for this q-row)
    const float* bp = bias_q + t * 64 + l4 * 4;
#pragma unroll
    for (int kj = 0; kj < 4; ++kj) {
      float4 bv = *reinterpret_cast<const float4*>(bp + kj * 16);
      st[kj][0] += bv.x;
      st[kj][1] += bv.y;
      st[kj][2] += bv.z;
      st[kj][3] += bv.w;
    }

    // online softmax over the 64 keys of this tile (row = q = l15)
    float mx = fmaxf(fmaxf(fmaxf(st[0][0], st[0][1]), fmaxf(st[0][2], st[0][3])),
                     fmaxf(fmaxf(st[1][0], st[1][1]), fmaxf(st[1][2], st[1][3])));
    mx = fmaxf(mx, fmaxf(fmaxf(fmaxf(st[2][0], st[2][1]), fmaxf(st[2][2], st[2][3])),
                         fmaxf(fmaxf(st[3][0], st[3][1]), fmaxf(st[3][2], st[3][3]))));
    mx = fmaxf(mx, __shfl_xor(mx, 16));
    mx = fmaxf(mx, __shfl_xor(mx, 32));
    float mn = fmaxf(m_run, mx);
    float alpha = __expf(m_run - mn);
    float rs = 0.f;
#pragma unroll
    for (int kj = 0; kj < 4; ++kj)
#pragma unroll
      for (int r = 0; r < 4; ++r) {
        float p = __expf(st[kj][r] - mn);
        st[kj][r] = p;
        rs += p;
      }
    rs += __shfl_xor(rs, 16);
    rs += __shfl_xor(rs, 32);
    l_run = l_run * alpha + rs;
    m_run = mn;
#pragma unroll
    for (int dj = 0; dj < 4; ++dj) {
      o_t[dj][0] *= alpha;
      o_t[dj][1] *= alpha;
      o_t[dj][2] *= alpha;
      o_t[dj][3] *= alpha;
    }

    // P^T (in regs) -> P row-major [q][key] in wave-local swizzled LDS
#pragma unroll
    for (int kj = 0; kj < 4; ++kj)
#pragma unroll
      for (int pr = 0; pr < 2; ++pr) {
        unsigned int v = cvt_pk_bf16(st[kj][2 * pr], st[kj][2 * pr + 1]);
        int idx = l15 * 32 + (((kj * 2 + (l4 >> 1)) ^ (l15 & 7)) * 4) + (l4 & 1) * 2 + pr;
        sPu[idx] = v;
      }

    // O^T += V^T P^T
    bf16x8 pb0 = ld_frag(sPw + l15 * 64 + ((l4 ^ (l15 & 7)) * 8));
    bf16x8 pb1 = ld_frag(sPw + l15 * 64 + (((4 + l4) ^ (l15 & 7)) * 8));
    __builtin_amdgcn_s_setprio(1);
#pragma unroll
    for (int dj = 0; dj < 4; ++dj) {
      int row = dj * 16 + l15;
      bf16x8 vf0 = ld_frag(sVc + row * 64 + ((l4 ^ (l15 & 7)) * 8));
      bf16x8 vf1 = ld_frag(sVc + row * 64 + (((4 + l4) ^ (l15 & 7)) * 8));
      o_t[dj] = mfma16(vf0, pb0, o_t[dj]);
      o_t[dj] = mfma16(vf1, pb1, o_t[dj]);
    }
    __builtin_amdgcn_s_setprio(0);

    __syncthreads();  // drains prefetch (vmcnt) + LDS, gates buffer swap
  }

  // epilogue: O = O^T / l, store (q-row = l15; cols d = dj*16 + l4*4 + r)
  float inv = 1.f / l_run;
  unsigned short* orow =
      Oatt + (size_t)(b * N_ + i0 + w * 16 + l15) * 1024 + h * 64 + l4 * 4;
#pragma unroll
  for (int dj = 0; dj < 4; ++dj) {
    union {
      unsigned short u[4];
      unsigned long long v;
    } pk;
    pk.u[0] = f2bf(o_t[dj][0] * inv);
    pk.u[1] = f2bf(o_t[dj][1] * inv);
    pk.u[2] = f2bf(o_t[dj][2] * inv);
    pk.u[3] = f2bf(o_t[dj][3] * inv);
    *reinterpret_cast<unsigned long long*>(orow + dj * 16) = pk.v;
  }
}

extern "C" void kernel_launch(void* const* d_in, const int* in_sizes, int n_in, void* d_out,
                              int out_size, void* d_ws, size_t ws_size, hipStream_t stream) {
  const float* x = (const float*)d_in[0];
  const float* bias = (const float*)d_in[1];
  const float* g = (const float*)d_in[2];
  const float* wq = (const float*)d_in[3];
  const float* wkv = (const float*)d_in[4];
  const float* wout = (const float*)d_in[5];
  float* out = (float*)d_out;

  float* ps = (float*)d_ws;
  float* pss = ps + 16 * B_ * DIM_;
  float* meanA = pss + 16 * B_ * DIM_;
  float* sclA = meanA + B_ * DIM_;
  unsigned short* xn = (unsigned short*)(sclA + B_ * DIM_);
  unsigned short* Wqkv = xn + (size_t)4096 * 1024;
  unsigned short* WoutB = Wqkv + (size_t)3072 * 1024;
  unsigned short* qkvb = WoutB + (size_t)1024 * 1024;
  unsigned short* Vt = qkvb + (size_t)4096 * 3072;
  unsigned short* Oatt = xn;  // alias: xn dead after QKV GEMM

  ln_part<<<dim3(DIM_ / 256, B_ * 16), 256, 0, stream>>>(x, ps, pss);
  ln_fin<<<dim3((B_ * DIM_) / 256), 256, 0, stream>>>(ps, pss, g, meanA, sclA);
  ln_apply<<<dim3((B_ * N_ * DIM_) / 2048), 256, 0, stream>>>(x, meanA, sclA, xn);
  cast_bf16<<<dim3((DIM_ * DIM_) / 2048), 256, 0, stream>>>(wq, Wqkv, 0.125f);
  cast_bf16<<<dim3((2 * DIM_ * DIM_) / 2048), 256, 0, stream>>>(wkv, Wqkv + (size_t)DIM_ * DIM_,
                                                                1.0f);
  cast_bf16<<<dim3((DIM_ * DIM_) / 2048), 256, 0, stream>>>(wout, WoutB, 1.0f);
  gemm_bt<false><<<dim3(3072 / 128, 4096 / 128), 256, 0, stream>>>(xn, Wqkv, qkvb, DIM_, 3072);
  transpose_v<<<dim3(N_ / 64, B_ * HEADS_), 256, 0, stream>>>(qkvb, Vt);
  flash_attn<<<dim3(N_ / 128, B_ * HEADS_), 512, 0, stream>>>(qkvb, bias, Vt, Oatt);
  gemm_bt<true><<<dim3(1024 / 128, 4096 / 128), 256, 0, stream>>>(Oatt, WoutB, out, DIM_, 1024);
}

// Round 4
// 194.576 us; speedup vs baseline: 1.1881x; 1.1147x over previous
//
#include <hip/hip_runtime.h>
#include <hip/hip_bf16.h>
#include <stdint.h>

#define B_ 2
#define N_ 2048
#define DIM_ 1024
#define HEADS_ 16
#define DH_ 64
#define EPS_ 1e-5f

typedef __attribute__((ext_vector_type(4))) float f32x4;
typedef __attribute__((ext_vector_type(8))) __bf16 bf16x8;
typedef __attribute__((ext_vector_type(4))) unsigned int u32x4;

__device__ __forceinline__ f32x4 mfma16(bf16x8 a, bf16x8 b, f32x4 c) {
  return __builtin_amdgcn_mfma_f32_16x16x32_bf16(a, b, c, 0, 0, 0);
}

__device__ __forceinline__ unsigned short f2bf(float x) {
  unsigned int u = __builtin_bit_cast(unsigned int, x);
  u += 0x7fffu + ((u >> 16) & 1u);
  return (unsigned short)(u >> 16);
}

__device__ __forceinline__ unsigned int cvt_pk_bf16(float lo, float hi) {
  unsigned int r;
  asm("v_cvt_pk_bf16_f32 %0, %1, %2" : "=v"(r) : "v"(lo), "v"(hi));
  return r;
}

__device__ __forceinline__ bf16x8 ld_frag(const unsigned short* p) {
  u32x4 v = *reinterpret_cast<const u32x4*>(p);
  return __builtin_bit_cast(bf16x8, v);
}

__device__ __forceinline__ void gload_lds16(const unsigned short* g, unsigned short* l) {
  __builtin_amdgcn_global_load_lds((const __attribute__((address_space(1))) void*)g,
                                   (__attribute__((address_space(3))) void*)l, 16, 0, 0);
}

// ---------------- LayerNorm over sequence axis ----------------
__global__ __launch_bounds__(256) void ln_part(const float* __restrict__ x,
                                               float* __restrict__ ps,
                                               float* __restrict__ pss) {
  const int d = blockIdx.x * 256 + threadIdx.x;
  const int b = blockIdx.y >> 4, sp = blockIdx.y & 15;
  const float* xp = x + (size_t)(b * N_ + sp * 128) * DIM_ + d;
  float s = 0.f, ss = 0.f;
  for (int i = 0; i < 128; ++i) {
    float v = xp[(size_t)i * DIM_];
    s += v;
    ss += v * v;
  }
  int c = b * DIM_ + d;
  ps[sp * (B_ * DIM_) + c] = s;
  pss[sp * (B_ * DIM_) + c] = ss;
}

__global__ void ln_fin(const float* __restrict__ ps, const float* __restrict__ pss,
                       const float* __restrict__ g, float* __restrict__ meanA,
                       float* __restrict__ sclA) {
  int c = blockIdx.x * 256 + threadIdx.x;
  float s = 0.f, ss = 0.f;
#pragma unroll
  for (int sp = 0; sp < 16; ++sp) {
    s += ps[sp * (B_ * DIM_) + c];
    ss += pss[sp * (B_ * DIM_) + c];
  }
  float m = s * (1.f / N_);
  float v = ss * (1.f / N_) - m * m;
  meanA[c] = m;
  sclA[c] = rsqrtf(fmaxf(v, EPS_)) * g[c & (DIM_ - 1)];
}

__global__ __launch_bounds__(256) void ln_apply(const float* __restrict__ x,
                                                const float* __restrict__ meanA,
                                                const float* __restrict__ sclA,
                                                unsigned short* __restrict__ xn) {
  size_t t = (size_t)blockIdx.x * 256 + threadIdx.x;
  size_t base = t * 8;
  int d0 = (int)(base & (DIM_ - 1));
  int b = base >= (size_t)N_ * DIM_;
  int c = b * DIM_ + d0;
  const float4* xp = reinterpret_cast<const float4*>(x + base);
  const float4* mp = reinterpret_cast<const float4*>(meanA + c);
  const float4* sp = reinterpret_cast<const float4*>(sclA + c);
  float4 x0 = xp[0], x1 = xp[1];
  float4 m0 = mp[0], m1 = mp[1];
  float4 s0 = sp[0], s1 = sp[1];
  union {
    unsigned short u[8];
    u32x4 v;
  } o;
  o.u[0] = f2bf((x0.x - m0.x) * s0.x);
  o.u[1] = f2bf((x0.y - m0.y) * s0.y);
  o.u[2] = f2bf((x0.z - m0.z) * s0.z);
  o.u[3] = f2bf((x0.w - m0.w) * s0.w);
  o.u[4] = f2bf((x1.x - m1.x) * s1.x);
  o.u[5] = f2bf((x1.y - m1.y) * s1.y);
  o.u[6] = f2bf((x1.z - m1.z) * s1.z);
  o.u[7] = f2bf((x1.w - m1.w) * s1.w);
  *reinterpret_cast<u32x4*>(xn + base) = o.v;
}

// ---------------- fp32 -> bf16 weight cast (optional scale) ----------------
__global__ __launch_bounds__(256) void cast_bf16(const float* __restrict__ src,
                                                 unsigned short* __restrict__ dst, float scale) {
  size_t t = (size_t)blockIdx.x * 256 + threadIdx.x;
  size_t base = t * 8;
  const float4* sp = reinterpret_cast<const float4*>(src + base);
  float4 a = sp[0], b4 = sp[1];
  union {
    unsigned short u[8];
    u32x4 v;
  } o;
  o.u[0] = f2bf(a.x * scale);
  o.u[1] = f2bf(a.y * scale);
  o.u[2] = f2bf(a.z * scale);
  o.u[3] = f2bf(a.w * scale);
  o.u[4] = f2bf(b4.x * scale);
  o.u[5] = f2bf(b4.y * scale);
  o.u[6] = f2bf(b4.z * scale);
  o.u[7] = f2bf(b4.w * scale);
  *reinterpret_cast<u32x4*>(dst + base) = o.v;
}

// ---------------- GEMM: C[M,Nc] = A[M,K]bf16 * W[Nc,K]bf16^T ----------------
template <bool OUT_F32>
__global__ __launch_bounds__(256) void gemm_bt(const unsigned short* __restrict__ A,
                                               const unsigned short* __restrict__ W,
                                               void* __restrict__ Cout, int K, int ldc) {
  __shared__ unsigned short sA[128 * 64];
  __shared__ unsigned short sB[128 * 64];
  const int tid = threadIdx.x, lane = tid & 63, w = tid >> 6;
  const int wm = w >> 1, wn = w & 1;
  const int l15 = lane & 15, l4 = lane >> 4;
  const int m0 = blockIdx.y * 128, n0 = blockIdx.x * 128;
  f32x4 acc[4][4] = {};
  for (int kt = 0; kt < K; kt += 64) {
    __syncthreads();
#pragma unroll
    for (int p = 0; p < 4; ++p) {
      int flat = p * 256 + tid;
      int row = flat >> 3, c = flat & 7;
      int cs = c ^ (row & 7);
      gload_lds16(A + (size_t)(m0 + row) * K + kt + cs * 8, sA + (size_t)(p * 256 + w * 64) * 8);
      gload_lds16(W + (size_t)(n0 + row) * K + kt + cs * 8, sB + (size_t)(p * 256 + w * 64) * 8);
    }
    __syncthreads();
#pragma unroll
    for (int kk = 0; kk < 2; ++kk) {
      bf16x8 af[4], bfr[4];
#pragma unroll
      for (int i = 0; i < 4; ++i) {
        int rowA = wm * 64 + i * 16 + l15;
        af[i] = ld_frag(sA + rowA * 64 + (((kk * 4 + l4) ^ (rowA & 7)) * 8));
        int rowB = wn * 64 + i * 16 + l15;
        bfr[i] = ld_frag(sB + rowB * 64 + (((kk * 4 + l4) ^ (rowB & 7)) * 8));
      }
#pragma unroll
      for (int i = 0; i < 4; ++i)
#pragma unroll
        for (int j = 0; j < 4; ++j) acc[i][j] = mfma16(af[i], bfr[j], acc[i][j]);
    }
  }
#pragma unroll
  for (int i = 0; i < 4; ++i)
#pragma unroll
    for (int j = 0; j < 4; ++j)
#pragma unroll
      for (int r = 0; r < 4; ++r) {
        size_t off =
            (size_t)(m0 + wm * 64 + i * 16 + l4 * 4 + r) * ldc + (n0 + wn * 64 + j * 16 + l15);
        if (OUT_F32)
          ((float*)Cout)[off] = acc[i][j][r];
        else
          ((unsigned short*)Cout)[off] = f2bf(acc[i][j][r]);
      }
}

// ---------------- V transpose: qkv v-block -> Vt[b][h][dh][n] ----------------
__global__ __launch_bounds__(256) void transpose_v(const unsigned short* __restrict__ qkv,
                                                   unsigned short* __restrict__ Vt) {
  __shared__ unsigned short tt[64][65];
  const int tid = threadIdx.x;
  const int h = blockIdx.y >> 1, b = blockIdx.y & 1;
  const int n0 = blockIdx.x * 64;
  const unsigned short* src = qkv + (size_t)(b * N_ + n0) * 3072 + 2048 + h * 64;
#pragma unroll
  for (int i = 0; i < 16; ++i) {
    int idx = i * 256 + tid;
    int r = idx >> 6, c = idx & 63;
    tt[r][c] = src[(size_t)r * 3072 + c];
  }
  __syncthreads();
  unsigned short* dst = Vt + (size_t)(b * HEADS_ + h) * 64 * N_ + n0;
#pragma unroll
  for (int i = 0; i < 16; ++i) {
    int idx = i * 256 + tid;
    int dh = idx >> 6, nn = idx & 63;
    dst[(size_t)dh * N_ + nn] = tt[nn][dh];
  }
}

// ---------------- Flash attention -------------------------------------------
// Swapped layout (S^T = K Q^T, O^T = V^T P^T), 8 waves x 16 q-rows,
// dbuf K/V via global_load_lds with counted-vmcnt barrier (T4),
// register double-buffered bias prefetch, XCD-swizzled block mapping.
// sched_barrier(0) after the gload_lds pair pins them OLDEST in the vmem
// queue so the vmcnt(4) drain is deterministic (bias x4 stay in flight).
__global__ __launch_bounds__(512, 4) void flash_attn(const unsigned short* __restrict__ qkv,
                                                     const float* __restrict__ bias,
                                                     const unsigned short* __restrict__ Vt,
                                                     unsigned short* __restrict__ Oatt) {
  __shared__ unsigned short sK[2][64 * 64];
  __shared__ unsigned short sV[2][64 * 64];
  __shared__ unsigned short sP[8 * 16 * 64];

  const int tid = threadIdx.x, lane = tid & 63, w = tid >> 6;
  const int l15 = lane & 15, l4 = lane >> 4;
  // XCD swizzle: id%8 ~ XCD. bh = id&31 -> all i-blocks of a head (both b)
  // share an XCD; K/V (512KB/head) and bias rows go L2-resident.
  const int r = blockIdx.x;
  const int bh = r & 31, iblk = r >> 5;
  const int h = bh & 15, b = bh >> 4;
  const int i0 = iblk * 128;

  const unsigned short* Kg = qkv + (size_t)b * N_ * 3072 + 1024 + h * 64;
  const unsigned short* VtB = Vt + (size_t)(b * HEADS_ + h) * 64 * N_;
  const float* bias_q =
      bias + (size_t)h * N_ * N_ + (size_t)(i0 + w * 16 + l15) * N_ + l4 * 4;

  const int srow = tid >> 3, sc = tid & 7;
  const int scs = sc ^ (srow & 7);
  const size_t kSrcOff = (size_t)srow * 3072 + (size_t)scs * 8;
  const size_t vSrcOff = (size_t)srow * N_ + (size_t)scs * 8;
  unsigned short* kDst0 = sK[0] + (size_t)w * 512;
  unsigned short* kDst1 = sK[1] + (size_t)w * 512;
  unsigned short* vDst0 = sV[0] + (size_t)w * 512;
  unsigned short* vDst1 = sV[1] + (size_t)w * 512;

  // Q straight to registers (B-operand frag: row q=l15, d-chunk l4)
  bf16x8 qf[2];
  {
    const unsigned short* Qg =
        qkv + (size_t)(b * N_ + i0 + w * 16 + l15) * 3072 + h * 64 + l4 * 8;
    qf[0] = ld_frag(Qg);
    qf[1] = ld_frag(Qg + 32);
  }

  f32x4 o_t[4] = {};
  float m_run = -1e30f, l_run = 0.f;
  const int sw = l15 & 7;

  unsigned int* sPu = reinterpret_cast<unsigned int*>(sP + (size_t)w * 16 * 64);
  const unsigned short* sPw = sP + (size_t)w * 16 * 64;

  float4 bbA[4], bbB[4];
  // prologue: stage tile 0 (LDS) + bias tile 0 (regs)
  gload_lds16(Kg + kSrcOff, kDst0);
  gload_lds16(VtB + vSrcOff, vDst0);
#pragma unroll
  for (int kj = 0; kj < 4; ++kj)
    bbA[kj] = *reinterpret_cast<const float4*>(bias_q + kj * 16);
  __syncthreads();

  const int NT = N_ / 64;
  auto body = [&](int t, const unsigned short* sKc, const unsigned short* sVc,
                  unsigned short* kDn, unsigned short* vDn, float4* bcur, float4* bnx) {
    // prefetch t+1: K/V -> LDS (other buffer) FIRST, then bias -> regs.
    if (t + 1 < NT) {
      const size_t jn = (size_t)(t + 1) * 64;
      gload_lds16(Kg + jn * 3072 + kSrcOff, kDn);
      gload_lds16(VtB + jn + vSrcOff, vDn);
      __builtin_amdgcn_sched_barrier(0);  // pin gloads oldest in vmem queue
#pragma unroll
      for (int kj = 0; kj < 4; ++kj)
        bnx[kj] = *reinterpret_cast<const float4*>(bias_q + jn + kj * 16);
    }

    // S^T = K Q^T
    f32x4 st[4];
    __builtin_amdgcn_s_setprio(1);
#pragma unroll
    for (int kj = 0; kj < 4; ++kj) {
      int row = kj * 16 + l15;
      bf16x8 kf0 = ld_frag(sKc + row * 64 + ((l4 ^ sw) * 8));
      bf16x8 kf1 = ld_frag(sKc + row * 64 + (((4 + l4) ^ sw) * 8));
      f32x4 z = {};
      z = mfma16(kf0, qf[0], z);
      st[kj] = mfma16(kf1, qf[1], z);
    }
    __builtin_amdgcn_s_setprio(0);

    // bias add from prefetched regs
#pragma unroll
    for (int kj = 0; kj < 4; ++kj) {
      st[kj][0] += bcur[kj].x;
      st[kj][1] += bcur[kj].y;
      st[kj][2] += bcur[kj].z;
      st[kj][3] += bcur[kj].w;
    }

    // online softmax over this tile's 64 keys (row = q = l15)
    float mx = fmaxf(fmaxf(fmaxf(st[0][0], st[0][1]), fmaxf(st[0][2], st[0][3])),
                     fmaxf(fmaxf(st[1][0], st[1][1]), fmaxf(st[1][2], st[1][3])));
    mx = fmaxf(mx, fmaxf(fmaxf(fmaxf(st[2][0], st[2][1]), fmaxf(st[2][2], st[2][3])),
                         fmaxf(fmaxf(st[3][0], st[3][1]), fmaxf(st[3][2], st[3][3]))));
    mx = fmaxf(mx, __shfl_xor(mx, 16));
    mx = fmaxf(mx, __shfl_xor(mx, 32));
    float mn = fmaxf(m_run, mx);
    float alpha = __expf(m_run - mn);
    float rs = 0.f;
#pragma unroll
    for (int kj = 0; kj < 4; ++kj)
#pragma unroll
      for (int rr = 0; rr < 4; ++rr) {
        float p = __expf(st[kj][rr] - mn);
        st[kj][rr] = p;
        rs += p;
      }
    rs += __shfl_xor(rs, 16);
    rs += __shfl_xor(rs, 32);
    l_run = l_run * alpha + rs;
    m_run = mn;
#pragma unroll
    for (int dj = 0; dj < 4; ++dj) {
      o_t[dj][0] *= alpha;
      o_t[dj][1] *= alpha;
      o_t[dj][2] *= alpha;
      o_t[dj][3] *= alpha;
    }

    // P^T (regs) -> P row-major [q][key] in wave-local swizzled LDS
#pragma unroll
    for (int kj = 0; kj < 4; ++kj)
#pragma unroll
      for (int pr = 0; pr < 2; ++pr) {
        unsigned int v = cvt_pk_bf16(st[kj][2 * pr], st[kj][2 * pr + 1]);
        int idx = l15 * 32 + (((kj * 2 + (l4 >> 1)) ^ sw) * 4) + (l4 & 1) * 2 + pr;
        sPu[idx] = v;
      }

    // O^T += V^T P^T
    bf16x8 pb0 = ld_frag(sPw + l15 * 64 + ((l4 ^ sw) * 8));
    bf16x8 pb1 = ld_frag(sPw + l15 * 64 + (((4 + l4) ^ sw) * 8));
    __builtin_amdgcn_s_setprio(1);
#pragma unroll
    for (int dj = 0; dj < 4; ++dj) {
      int row = dj * 16 + l15;
      bf16x8 vf0 = ld_frag(sVc + row * 64 + ((l4 ^ sw) * 8));
      bf16x8 vf1 = ld_frag(sVc + row * 64 + (((4 + l4) ^ sw) * 8));
      o_t[dj] = mfma16(vf0, pb0, o_t[dj]);
      o_t[dj] = mfma16(vf1, pb1, o_t[dj]);
    }
    __builtin_amdgcn_s_setprio(0);

    if (t != NT - 1) {
      // counted drain: the 2 gload_lds issued this tile are the oldest
      // outstanding vmem ops (pinned above); drain exactly them. The 4 bias
      // loads (newest) stay in flight across the barrier.
      asm volatile("s_waitcnt vmcnt(4)" ::: "memory");
      __builtin_amdgcn_s_barrier();
    }
  };

  for (int t = 0; t < NT; t += 2) {
    body(t, sK[0], sV[0], kDst1, vDst1, bbA, bbB);
    body(t + 1, sK[1], sV[1], kDst0, vDst0, bbB, bbA);
  }

  // epilogue: O = O^T / l, store (q-row = l15; cols d = dj*16 + l4*4 + r)
  float inv = 1.f / l_run;
  unsigned short* orow =
      Oatt + (size_t)(b * N_ + i0 + w * 16 + l15) * 1024 + h * 64 + l4 * 4;
#pragma unroll
  for (int dj = 0; dj < 4; ++dj) {
    union {
      unsigned short u[4];
      unsigned long long v;
    } pk;
    pk.u[0] = f2bf(o_t[dj][0] * inv);
    pk.u[1] = f2bf(o_t[dj][1] * inv);
    pk.u[2] = f2bf(o_t[dj][2] * inv);
    pk.u[3] = f2bf(o_t[dj][3] * inv);
    *reinterpret_cast<unsigned long long*>(orow + dj * 16) = pk.v;
  }
}

extern "C" void kernel_launch(void* const* d_in, const int* in_sizes, int n_in, void* d_out,
                              int out_size, void* d_ws, size_t ws_size, hipStream_t stream) {
  const float* x = (const float*)d_in[0];
  const float* bias = (const float*)d_in[1];
  const float* g = (const float*)d_in[2];
  const float* wq = (const float*)d_in[3];
  const float* wkv = (const float*)d_in[4];
  const float* wout = (const float*)d_in[5];
  float* out = (float*)d_out;

  float* ps = (float*)d_ws;
  float* pss = ps + 16 * B_ * DIM_;
  float* meanA = pss + 16 * B_ * DIM_;
  float* sclA = meanA + B_ * DIM_;
  unsigned short* xn = (unsigned short*)(sclA + B_ * DIM_);
  unsigned short* Wqkv = xn + (size_t)4096 * 1024;
  unsigned short* WoutB = Wqkv + (size_t)3072 * 1024;
  unsigned short* qkvb = WoutB + (size_t)1024 * 1024;
  unsigned short* Vt = qkvb + (size_t)4096 * 3072;
  unsigned short* Oatt = xn;  // alias: xn dead after QKV GEMM

  ln_part<<<dim3(DIM_ / 256, B_ * 16), 256, 0, stream>>>(x, ps, pss);
  ln_fin<<<dim3((B_ * DIM_) / 256), 256, 0, stream>>>(ps, pss, g, meanA, sclA);
  ln_apply<<<dim3((B_ * N_ * DIM_) / 2048), 256, 0, stream>>>(x, meanA, sclA, xn);
  cast_bf16<<<dim3((DIM_ * DIM_) / 2048), 256, 0, stream>>>(wq, Wqkv, 0.125f);
  cast_bf16<<<dim3((2 * DIM_ * DIM_) / 2048), 256, 0, stream>>>(wkv, Wqkv + (size_t)DIM_ * DIM_,
                                                                1.0f);
  cast_bf16<<<dim3((DIM_ * DIM_) / 2048), 256, 0, stream>>>(wout, WoutB, 1.0f);
  gemm_bt<false><<<dim3(3072 / 128, 4096 / 128), 256, 0, stream>>>(xn, Wqkv, qkvb, DIM_, 3072);
  transpose_v<<<dim3(N_ / 64, B_ * HEADS_), 256, 0, stream>>>(qkvb, Vt);
  flash_attn<<<dim3(512), 512, 0, stream>>>(qkvb, bias, Vt, Oatt);
  gemm_bt<true><<<dim3(1024 / 128, 4096 / 128), 256, 0, stream>>>(Oatt, WoutB, out, DIM_, 1024);
}

// Round 5
// 190.156 us; speedup vs baseline: 1.2157x; 1.0232x over previous
//
#include <hip/hip_runtime.h>
#include <hip/hip_bf16.h>
#include <stdint.h>

#define B_ 2
#define N_ 2048
#define DIM_ 1024
#define HEADS_ 16
#define DH_ 64
#define EPS_ 1e-5f

typedef __attribute__((ext_vector_type(4))) float f32x4;
typedef __attribute__((ext_vector_type(8))) __bf16 bf16x8;
typedef __attribute__((ext_vector_type(4))) unsigned int u32x4;

__device__ __forceinline__ f32x4 mfma16(bf16x8 a, bf16x8 b, f32x4 c) {
  return __builtin_amdgcn_mfma_f32_16x16x32_bf16(a, b, c, 0, 0, 0);
}

__device__ __forceinline__ unsigned short f2bf(float x) {
  unsigned int u = __builtin_bit_cast(unsigned int, x);
  u += 0x7fffu + ((u >> 16) & 1u);
  return (unsigned short)(u >> 16);
}

__device__ __forceinline__ unsigned int cvt_pk_bf16(float lo, float hi) {
  unsigned int r;
  asm("v_cvt_pk_bf16_f32 %0, %1, %2" : "=v"(r) : "v"(lo), "v"(hi));
  return r;
}

__device__ __forceinline__ bf16x8 ld_frag(const unsigned short* p) {
  u32x4 v = *reinterpret_cast<const u32x4*>(p);
  return __builtin_bit_cast(bf16x8, v);
}

__device__ __forceinline__ void gload_lds16(const unsigned short* g, unsigned short* l) {
  __builtin_amdgcn_global_load_lds((const __attribute__((address_space(1))) void*)g,
                                   (__attribute__((address_space(3))) void*)l, 16, 0, 0);
}

// ---------------- LayerNorm over sequence axis ----------------
__global__ __launch_bounds__(256) void ln_part(const float* __restrict__ x,
                                               float* __restrict__ ps,
                                               float* __restrict__ pss) {
  const int d = blockIdx.x * 256 + threadIdx.x;
  const int b = blockIdx.y >> 4, sp = blockIdx.y & 15;
  const float* xp = x + (size_t)(b * N_ + sp * 128) * DIM_ + d;
  float s = 0.f, ss = 0.f;
  for (int i = 0; i < 128; ++i) {
    float v = xp[(size_t)i * DIM_];
    s += v;
    ss += v * v;
  }
  int c = b * DIM_ + d;
  ps[sp * (B_ * DIM_) + c] = s;
  pss[sp * (B_ * DIM_) + c] = ss;
}

__global__ void ln_fin(const float* __restrict__ ps, const float* __restrict__ pss,
                       const float* __restrict__ g, float* __restrict__ meanA,
                       float* __restrict__ sclA) {
  int c = blockIdx.x * 256 + threadIdx.x;
  float s = 0.f, ss = 0.f;
#pragma unroll
  for (int sp = 0; sp < 16; ++sp) {
    s += ps[sp * (B_ * DIM_) + c];
    ss += pss[sp * (B_ * DIM_) + c];
  }
  float m = s * (1.f / N_);
  float v = ss * (1.f / N_) - m * m;
  meanA[c] = m;
  sclA[c] = rsqrtf(fmaxf(v, EPS_)) * g[c & (DIM_ - 1)];
}

__global__ __launch_bounds__(256) void ln_apply(const float* __restrict__ x,
                                                const float* __restrict__ meanA,
                                                const float* __restrict__ sclA,
                                                unsigned short* __restrict__ xn) {
  size_t t = (size_t)blockIdx.x * 256 + threadIdx.x;
  size_t base = t * 8;
  int d0 = (int)(base & (DIM_ - 1));
  int b = base >= (size_t)N_ * DIM_;
  int c = b * DIM_ + d0;
  const float4* xp = reinterpret_cast<const float4*>(x + base);
  const float4* mp = reinterpret_cast<const float4*>(meanA + c);
  const float4* sp = reinterpret_cast<const float4*>(sclA + c);
  float4 x0 = xp[0], x1 = xp[1];
  float4 m0 = mp[0], m1 = mp[1];
  float4 s0 = sp[0], s1 = sp[1];
  union {
    unsigned short u[8];
    u32x4 v;
  } o;
  o.u[0] = f2bf((x0.x - m0.x) * s0.x);
  o.u[1] = f2bf((x0.y - m0.y) * s0.y);
  o.u[2] = f2bf((x0.z - m0.z) * s0.z);
  o.u[3] = f2bf((x0.w - m0.w) * s0.w);
  o.u[4] = f2bf((x1.x - m1.x) * s1.x);
  o.u[5] = f2bf((x1.y - m1.y) * s1.y);
  o.u[6] = f2bf((x1.z - m1.z) * s1.z);
  o.u[7] = f2bf((x1.w - m1.w) * s1.w);
  *reinterpret_cast<u32x4*>(xn + base) = o.v;
}

// ---------------- fp32 -> bf16 weight cast (optional scale) ----------------
__global__ __launch_bounds__(256) void cast_bf16(const float* __restrict__ src,
                                                 unsigned short* __restrict__ dst, float scale) {
  size_t t = (size_t)blockIdx.x * 256 + threadIdx.x;
  size_t base = t * 8;
  const float4* sp = reinterpret_cast<const float4*>(src + base);
  float4 a = sp[0], b4 = sp[1];
  union {
    unsigned short u[8];
    u32x4 v;
  } o;
  o.u[0] = f2bf(a.x * scale);
  o.u[1] = f2bf(a.y * scale);
  o.u[2] = f2bf(a.z * scale);
  o.u[3] = f2bf(a.w * scale);
  o.u[4] = f2bf(b4.x * scale);
  o.u[5] = f2bf(b4.y * scale);
  o.u[6] = f2bf(b4.z * scale);
  o.u[7] = f2bf(b4.w * scale);
  *reinterpret_cast<u32x4*>(dst + base) = o.v;
}

// ---------------- GEMM: C[M,Nc] = A[M,K]bf16 * W[Nc,K]bf16^T ----------------
template <bool OUT_F32>
__global__ __launch_bounds__(256) void gemm_bt(const unsigned short* __restrict__ A,
                                               const unsigned short* __restrict__ W,
                                               void* __restrict__ Cout, int K, int ldc) {
  __shared__ unsigned short sA[128 * 64];
  __shared__ unsigned short sB[128 * 64];
  const int tid = threadIdx.x, lane = tid & 63, w = tid >> 6;
  const int wm = w >> 1, wn = w & 1;
  const int l15 = lane & 15, l4 = lane >> 4;
  const int m0 = blockIdx.y * 128, n0 = blockIdx.x * 128;
  f32x4 acc[4][4] = {};
  for (int kt = 0; kt < K; kt += 64) {
    __syncthreads();
#pragma unroll
    for (int p = 0; p < 4; ++p) {
      int flat = p * 256 + tid;
      int row = flat >> 3, c = flat & 7;
      int cs = c ^ (row & 7);
      gload_lds16(A + (size_t)(m0 + row) * K + kt + cs * 8, sA + (size_t)(p * 256 + w * 64) * 8);
      gload_lds16(W + (size_t)(n0 + row) * K + kt + cs * 8, sB + (size_t)(p * 256 + w * 64) * 8);
    }
    __syncthreads();
#pragma unroll
    for (int kk = 0; kk < 2; ++kk) {
      bf16x8 af[4], bfr[4];
#pragma unroll
      for (int i = 0; i < 4; ++i) {
        int rowA = wm * 64 + i * 16 + l15;
        af[i] = ld_frag(sA + rowA * 64 + (((kk * 4 + l4) ^ (rowA & 7)) * 8));
        int rowB = wn * 64 + i * 16 + l15;
        bfr[i] = ld_frag(sB + rowB * 64 + (((kk * 4 + l4) ^ (rowB & 7)) * 8));
      }
#pragma unroll
      for (int i = 0; i < 4; ++i)
#pragma unroll
        for (int j = 0; j < 4; ++j) acc[i][j] = mfma16(af[i], bfr[j], acc[i][j]);
    }
  }
#pragma unroll
  for (int i = 0; i < 4; ++i)
#pragma unroll
    for (int j = 0; j < 4; ++j)
#pragma unroll
      for (int r = 0; r < 4; ++r) {
        size_t off =
            (size_t)(m0 + wm * 64 + i * 16 + l4 * 4 + r) * ldc + (n0 + wn * 64 + j * 16 + l15);
        if (OUT_F32)
          ((float*)Cout)[off] = acc[i][j][r];
        else
          ((unsigned short*)Cout)[off] = f2bf(acc[i][j][r]);
      }
}

// ---------------- V transpose: qkv v-block -> Vt[b][h][dh][n] ----------------
__global__ __launch_bounds__(256) void transpose_v(const unsigned short* __restrict__ qkv,
                                                   unsigned short* __restrict__ Vt) {
  __shared__ unsigned short tt[64][65];
  const int tid = threadIdx.x;
  const int h = blockIdx.y >> 1, b = blockIdx.y & 1;
  const int n0 = blockIdx.x * 64;
  const unsigned short* src = qkv + (size_t)(b * N_ + n0) * 3072 + 2048 + h * 64;
#pragma unroll
  for (int i = 0; i < 16; ++i) {
    int idx = i * 256 + tid;
    int r = idx >> 6, c = idx & 63;
    tt[r][c] = src[(size_t)r * 3072 + c];
  }
  __syncthreads();
  unsigned short* dst = Vt + (size_t)(b * HEADS_ + h) * 64 * N_ + n0;
#pragma unroll
  for (int i = 0; i < 16; ++i) {
    int idx = i * 256 + tid;
    int dh = idx >> 6, nn = idx & 63;
    dst[(size_t)dh * N_ + nn] = tt[nn][dh];
  }
}

// ---------------- Flash attention -------------------------------------------
// Swapped layout (S^T = K Q^T, O^T = V^T P^T), 8 waves x 16 q-rows.
// Bias tile is prefetched INTO the score array and consumed as the MFMA
// C-operand (no separate bias registers, no bias-add VALU). All per-tile
// state is in named, statically-indexed register arrays (no lambda, no
// pointer-indexed arrays) so it fits the 128-VGPR cap of (512,4) w/o spills.
__global__ __launch_bounds__(512, 4) void flash_attn(const unsigned short* __restrict__ qkv,
                                                     const float* __restrict__ bias,
                                                     const unsigned short* __restrict__ Vt,
                                                     unsigned short* __restrict__ Oatt) {
  __shared__ unsigned short sK[2][64 * 64];
  __shared__ unsigned short sV[2][64 * 64];
  __shared__ unsigned short sP[8 * 16 * 64];

  const int tid = threadIdx.x, lane = tid & 63, w = tid >> 6;
  const int l15 = lane & 15, l4 = lane >> 4;
  // XCD swizzle: id&7 ~ XCD; bh = id&31 keeps all i-blocks of a head (both b)
  // on one XCD -> K/V + bias rows L2-resident.
  const int r = blockIdx.x;
  const int bh = r & 31, iblk = r >> 5;
  const int h = bh & 15, b = bh >> 4;
  const int i0 = iblk * 128;

  const unsigned short* Kg = qkv + (size_t)b * N_ * 3072 + 1024 + h * 64;
  const unsigned short* VtB = Vt + (size_t)(b * HEADS_ + h) * 64 * N_;
  const float* bias_q =
      bias + (size_t)h * N_ * N_ + (size_t)(i0 + w * 16 + l15) * N_ + l4 * 4;

  const int srow = tid >> 3, sc = tid & 7;
  const int scs = sc ^ (srow & 7);
  const size_t kSrcOff = (size_t)srow * 3072 + (size_t)scs * 8;
  const size_t vSrcOff = (size_t)srow * N_ + (size_t)scs * 8;
  unsigned short* kDst0 = sK[0] + (size_t)w * 512;
  unsigned short* kDst1 = sK[1] + (size_t)w * 512;
  unsigned short* vDst0 = sV[0] + (size_t)w * 512;
  unsigned short* vDst1 = sV[1] + (size_t)w * 512;

  // Q straight to registers (B-operand frag: row q=l15, d-chunk l4)
  bf16x8 qf[2];
  {
    const unsigned short* Qg =
        qkv + (size_t)(b * N_ + i0 + w * 16 + l15) * 3072 + h * 64 + l4 * 8;
    qf[0] = ld_frag(Qg);
    qf[1] = ld_frag(Qg + 32);
  }

  f32x4 o_t[4] = {};
  f32x4 stA[4], stB[4];  // score/bias ping-pong (statically indexed only)
  float m_run = -1e30f, l_run = 0.f;
  const int sw = l15 & 7;

  unsigned int* sPu = reinterpret_cast<unsigned int*>(sP + (size_t)w * 16 * 64);
  const unsigned short* sPw = sP + (size_t)w * 16 * 64;

  // prologue: stage K/V tile 0 (LDS) + bias tile 0 -> stA
  gload_lds16(Kg + kSrcOff, kDst0);
  gload_lds16(VtB + vSrcOff, vDst0);
  stA[0] = *reinterpret_cast<const f32x4*>(bias_q);
  stA[1] = *reinterpret_cast<const f32x4*>(bias_q + 16);
  stA[2] = *reinterpret_cast<const f32x4*>(bias_q + 32);
  stA[3] = *reinterpret_cast<const f32x4*>(bias_q + 48);
  __syncthreads();

  const int NT = N_ / 64;

#define TILE_BODY(T, SKC, SVC, KDN, VDN, SC, SN)                               \
  {                                                                            \
    if ((T) + 1 < NT) {                                                        \
      const size_t jn = (size_t)((T) + 1) * 64;                                \
      gload_lds16(Kg + jn * 3072 + kSrcOff, KDN);                              \
      gload_lds16(VtB + jn + vSrcOff, VDN);                                    \
      __builtin_amdgcn_sched_barrier(0); /* pin gloads oldest in vmem queue */ \
      SN[0] = *reinterpret_cast<const f32x4*>(bias_q + jn);                    \
      SN[1] = *reinterpret_cast<const f32x4*>(bias_q + jn + 16);               \
      SN[2] = *reinterpret_cast<const f32x4*>(bias_q + jn + 32);               \
      SN[3] = *reinterpret_cast<const f32x4*>(bias_q + jn + 48);               \
    }                                                                          \
    /* S^T = K Q^T + bias (bias already in SC as the C-operand) */             \
    __builtin_amdgcn_s_setprio(1);                                             \
    _Pragma("unroll") for (int kj = 0; kj < 4; ++kj) {                         \
      int row = kj * 16 + l15;                                                 \
      bf16x8 kf0 = ld_frag(SKC + row * 64 + ((l4 ^ sw) * 8));                  \
      bf16x8 kf1 = ld_frag(SKC + row * 64 + (((4 + l4) ^ sw) * 8));            \
      SC[kj] = mfma16(kf0, qf[0], SC[kj]);                                     \
      SC[kj] = mfma16(kf1, qf[1], SC[kj]);                                     \
    }                                                                          \
    __builtin_amdgcn_s_setprio(0);                                             \
    /* online softmax over this tile's 64 keys (row = q = l15) */              \
    float mx = fmaxf(fmaxf(fmaxf(SC[0][0], SC[0][1]), fmaxf(SC[0][2], SC[0][3])), \
                     fmaxf(fmaxf(SC[1][0], SC[1][1]), fmaxf(SC[1][2], SC[1][3]))); \
    mx = fmaxf(mx, fmaxf(fmaxf(fmaxf(SC[2][0], SC[2][1]), fmaxf(SC[2][2], SC[2][3])), \
                         fmaxf(fmaxf(SC[3][0], SC[3][1]), fmaxf(SC[3][2], SC[3][3])))); \
    mx = fmaxf(mx, __shfl_xor(mx, 16));                                        \
    mx = fmaxf(mx, __shfl_xor(mx, 32));                                        \
    float mn = fmaxf(m_run, mx);                                               \
    float alpha = __expf(m_run - mn);                                          \
    float rs = 0.f;                                                            \
    _Pragma("unroll") for (int kj = 0; kj < 4; ++kj) {                         \
      _Pragma("unroll") for (int rr = 0; rr < 4; ++rr) {                       \
        float p = __expf(SC[kj][rr] - mn);                                     \
        SC[kj][rr] = p;                                                        \
        rs += p;                                                               \
      }                                                                        \
    }                                                                          \
    rs += __shfl_xor(rs, 16);                                                  \
    rs += __shfl_xor(rs, 32);                                                  \
    l_run = l_run * alpha + rs;                                                \
    m_run = mn;                                                                \
    _Pragma("unroll") for (int dj = 0; dj < 4; ++dj) {                         \
      o_t[dj][0] *= alpha;                                                     \
      o_t[dj][1] *= alpha;                                                     \
      o_t[dj][2] *= alpha;                                                     \
      o_t[dj][3] *= alpha;                                                     \
    }                                                                          \
    /* P^T (regs) -> P row-major [q][key], b64 writes, all 32 banks hit */     \
    _Pragma("unroll") for (int kj = 0; kj < 4; ++kj) {                         \
      unsigned int v0 = cvt_pk_bf16(SC[kj][0], SC[kj][1]);                     \
      unsigned int v1 = cvt_pk_bf16(SC[kj][2], SC[kj][3]);                     \
      int cc = (kj * 2 + (l4 >> 1)) ^ sw;                                      \
      uint2 pv;                                                                \
      pv.x = v0;                                                               \
      pv.y = v1;                                                               \
      *reinterpret_cast<uint2*>(sPu + l15 * 32 + cc * 4 + (l4 & 1) * 2) = pv;  \
    }                                                                          \
    /* O^T += V^T P^T */                                                       \
    bf16x8 pb0 = ld_frag(sPw + l15 * 64 + ((l4 ^ sw) * 8));                    \
    bf16x8 pb1 = ld_frag(sPw + l15 * 64 + (((4 + l4) ^ sw) * 8));              \
    __builtin_amdgcn_s_setprio(1);                                             \
    _Pragma("unroll") for (int dj = 0; dj < 4; ++dj) {                         \
      int row = dj * 16 + l15;                                                 \
      bf16x8 vf0 = ld_frag(SVC + row * 64 + ((l4 ^ sw) * 8));                  \
      bf16x8 vf1 = ld_frag(SVC + row * 64 + (((4 + l4) ^ sw) * 8));            \
      o_t[dj] = mfma16(vf0, pb0, o_t[dj]);                                     \
      o_t[dj] = mfma16(vf1, pb1, o_t[dj]);                                     \
    }                                                                          \
    __builtin_amdgcn_s_setprio(0);                                             \
    if ((T) != NT - 1) {                                                       \
      /* drain only the 2 oldest vmem ops (this tile's gload_lds); the 4 */    \
      /* bias loads (newest) stay in flight across the barrier */              \
      asm volatile("s_waitcnt vmcnt(4)" ::: "memory");                         \
      __builtin_amdgcn_s_barrier();                                            \
    }                                                                          \
  }

  const unsigned short* sK0c = sK[0];
  const unsigned short* sK1c = sK[1];
  const unsigned short* sV0c = sV[0];
  const unsigned short* sV1c = sV[1];
  for (int t = 0; t < NT; t += 2) {
    TILE_BODY(t, sK0c, sV0c, kDst1, vDst1, stA, stB)
    TILE_BODY(t + 1, sK1c, sV1c, kDst0, vDst0, stB, stA)
  }
#undef TILE_BODY

  // epilogue: O = O^T / l, store (q-row = l15; cols d = dj*16 + l4*4 + r)
  float inv = 1.f / l_run;
  unsigned short* orow =
      Oatt + (size_t)(b * N_ + i0 + w * 16 + l15) * 1024 + h * 64 + l4 * 4;
#pragma unroll
  for (int dj = 0; dj < 4; ++dj) {
    union {
      unsigned short u[4];
      unsigned long long v;
    } pk;
    pk.u[0] = f2bf(o_t[dj][0] * inv);
    pk.u[1] = f2bf(o_t[dj][1] * inv);
    pk.u[2] = f2bf(o_t[dj][2] * inv);
    pk.u[3] = f2bf(o_t[dj][3] * inv);
    *reinterpret_cast<unsigned long long*>(orow + dj * 16) = pk.v;
  }
}

extern "C" void kernel_launch(void* const* d_in, const int* in_sizes, int n_in, void* d_out,
                              int out_size, void* d_ws, size_t ws_size, hipStream_t stream) {
  const float* x = (const float*)d_in[0];
  const float* bias = (const float*)d_in[1];
  const float* g = (const float*)d_in[2];
  const float* wq = (const float*)d_in[3];
  const float* wkv = (const float*)d_in[4];
  const float* wout = (const float*)d_in[5];
  float* out = (float*)d_out;

  float* ps = (float*)d_ws;
  float* pss = ps + 16 * B_ * DIM_;
  float* meanA = pss + 16 * B_ * DIM_;
  float* sclA = meanA + B_ * DIM_;
  unsigned short* xn = (unsigned short*)(sclA + B_ * DIM_);
  unsigned short* Wqkv = xn + (size_t)4096 * 1024;
  unsigned short* WoutB = Wqkv + (size_t)3072 * 1024;
  unsigned short* qkvb = WoutB + (size_t)1024 * 1024;
  unsigned short* Vt = qkvb + (size_t)4096 * 3072;
  unsigned short* Oatt = xn;  // alias: xn dead after QKV GEMM

  ln_part<<<dim3(DIM_ / 256, B_ * 16), 256, 0, stream>>>(x, ps, pss);
  ln_fin<<<dim3((B_ * DIM_) / 256), 256, 0, stream>>>(ps, pss, g, meanA, sclA);
  ln_apply<<<dim3((B_ * N_ * DIM_) / 2048), 256, 0, stream>>>(x, meanA, sclA, xn);
  cast_bf16<<<dim3((DIM_ * DIM_) / 2048), 256, 0, stream>>>(wq, Wqkv, 0.125f);
  cast_bf16<<<dim3((2 * DIM_ * DIM_) / 2048), 256, 0, stream>>>(wkv, Wqkv + (size_t)DIM_ * DIM_,
                                                                1.0f);
  cast_bf16<<<dim3((DIM_ * DIM_) / 2048), 256, 0, stream>>>(wout, WoutB, 1.0f);
  gemm_bt<false><<<dim3(3072 / 128, 4096 / 128), 256, 0, stream>>>(xn, Wqkv, qkvb, DIM_, 3072);
  transpose_v<<<dim3(N_ / 64, B_ * HEADS_), 256, 0, stream>>>(qkvb, Vt);
  flash_attn<<<dim3(512), 512, 0, stream>>>(qkvb, bias, Vt, Oatt);
  gemm_bt<true><<<dim3(1024 / 128, 4096 / 128), 256, 0, stream>>>(Oatt, WoutB, out, DIM_, 1024);
}